// Round 1
// 1038.715 us; speedup vs baseline: 1.0508x; 1.0508x over previous
//
#include <hip/hip_runtime.h>
#include <hip/hip_bf16.h>
#include <stdint.h>

// Problem sizes (fixed by reference)
#define T_DIM 2048
#define N_DIM 64
#define E_DIM 1024
#define D_DIM 1024
#define A_DIM 512
#define M_DIM (T_DIM * N_DIM)  // 131072 rows of the big GEMM

typedef unsigned short u16;
typedef unsigned int   u32;
typedef float  floatx4 __attribute__((ext_vector_type(4)));
typedef __bf16 bf16x8  __attribute__((ext_vector_type(8)));
typedef u16    u16x8   __attribute__((ext_vector_type(8)));
typedef u32    u32x4   __attribute__((ext_vector_type(4)));

// tanh(x) = 1 - 2/(exp(2x)+1); safe at +/-inf, ~1e-6 abs err
__device__ __forceinline__ float fast_tanh(float x) {
  float e = __expf(2.0f * x);
  return 1.0f - 2.0f * __builtin_amdgcn_rcpf(e + 1.0f);
}

// Read 8 fp32 (data chunks q2 and q2+1 of a 32-float LDS row that is stored
// chunk-swizzled: data chunk c lives at position c ^ (row&7)) and truncate to
// bf16x8. Two independent 16B loads since the swizzle breaks 32B adjacency.
__device__ __forceinline__ bf16x8 pack8_swz(const float* rowp, int q2, int s) {
  u32x4 a = *(const u32x4*)(rowp + (((q2)     ^ s) << 2));
  u32x4 b = *(const u32x4*)(rowp + (((q2 + 1) ^ s) << 2));
  u16x8 r;
#pragma unroll
  for (int j = 0; j < 4; ++j) r[j] = (u16)(a[j] >> 16);
#pragma unroll
  for (int j = 0; j < 4; ++j) r[4 + j] = (u16)(b[j] >> 16);
  return __builtin_bit_cast(bf16x8, r);
}

// ---------------------------------------------------------------------------
// Kernel 1: d_proj[n][a] = sum_d dec_h[n][d] * W_d[a][d]   (fp32, exact)
// grid 512 (one block per a), 256 threads: 4 threads per n, each 256 d's.
// ---------------------------------------------------------------------------
__global__ __launch_bounds__(256) void dproj_kernel(
    const float* __restrict__ dec_h, const float* __restrict__ W_d,
    float* __restrict__ dproj) {
  const int a   = blockIdx.x;
  const int tid = threadIdx.x;
  const int n   = tid >> 2;
  const int kc  = (tid & 3) * 256;
  const float* dh = dec_h + n * D_DIM + kc;
  const float* wd = W_d   + a * D_DIM + kc;
  float s = 0.f;
#pragma unroll
  for (int i = 0; i < 256; i += 4) {
    floatx4 d4 = *(const floatx4*)(dh + i);
    floatx4 w4 = *(const floatx4*)(wd + i);
#pragma unroll
    for (int j = 0; j < 4; ++j) s += d4[j] * w4[j];
  }
  s += __shfl_xor(s, 1, 64);
  s += __shfl_xor(s, 2, 64);
  if ((tid & 3) == 0) dproj[n * A_DIM + a] = s;
}

// ---------------------------------------------------------------------------
// Kernel 2: fused GEMM + tanh + v-dot -> scores[t*64+n] (fp32, atomicAdd)
//   C[m][a] = sum_e enc2d[m][e] * W_e[a][e]   (NT: both row-major over K)
//   scores[m] += sum_a tanh(C[m][a] + dproj[n][a]) * v[a]
// fp32 inputs staged to LDS via global_load_lds(16B = 4 floats/lane),
// truncated to bf16 fragments in-register, 16x16x32 bf16 MFMA.
// 128x128 tile, BK=32, 4 waves (2x2 of 64x64 per wave).
//
// LDS swizzle (both-sides, rule #21): a tile row is 32 fp32 = 128 B = exactly
// 32 banks, so pre-swizzle bank index depended only on the 16B chunk position
// -> 16 lane-touches/bank vs the structural 8 for ds_read_b128 (2x LDS
// serialization, SQ_LDS_BANK_CONFLICT ~1e8). Fix: data chunk c of row r is
// stored at position c ^ (r&7). global_load_lds writes linearly (uniform base
// + lane*16B), so the swizzle is applied on the *global source* address at
// staging and on the position at ds_read. Post-fix every bank gets exactly 8
// touches per b128 -> conflict-free.
//
// XCD swizzle: 4096 blocks, 8 XCDs -> bijective remap so each XCD owns a
// contiguous range of 128 m-tiles with the 4 a-tile variants adjacent in
// dispatch order; the 4x enc re-read then hits that XCD's L2 instead of HBM.
// ---------------------------------------------------------------------------
__global__ __launch_bounds__(256) void score_gemm(
    const float* __restrict__ enc, const float* __restrict__ We,
    const float* __restrict__ dproj, const float* __restrict__ vv,
    float* __restrict__ scores) {
  __shared__ float sA[128 * 32];  // [row][chunk-swizzled k] fp32 (16 KB)
  __shared__ float sB[128 * 32];

  // XCD-aware bijective swizzle (grid = dim3(4,1024), x fastest; nwg=4096%8==0)
  const int lin = (int)blockIdx.y * 4 + (int)blockIdx.x;
  const int swz = (lin & 7) * (4096 / 8) + (lin >> 3);
  const int a0 = (swz & 3) * 128;   // a-tile fastest within an XCD
  const int m0 = (swz >> 2) * 128;

  const int tid  = threadIdx.x;
  const int lane = tid & 63;
  const int w    = tid >> 6;        // wave 0..3
  const int wm   = w >> 1;          // wave row (0..1)
  const int wn   = w & 1;           // wave col (0..1)
  const int quad = lane >> 4;
  const int l15  = lane & 15;

  // staging: each global_load_lds covers 8 rows (64 lanes x 16B = 1KB,
  // row = 32 floats = 128B). LDS dest = wave-uniform base + lane*16B:
  // lane>>3 = row-in-8, lane&7 = chunk position. Source chunk is
  // pre-swizzled: chunk ^ (row&7), so LDS(r, p) holds data chunk p^(r&7).
  const int srow = lane >> 3;
  const int skc  = ((lane & 7) ^ srow) * 4;  // pre-swizzled source col (floats)

  floatx4 acc[4][4] = {};

  const float* gA = enc + (size_t)m0 * E_DIM;
  const float* gB = We  + (size_t)a0 * E_DIM;

  for (int k0 = 0; k0 < E_DIM; k0 += 32) {
    __syncthreads();  // previous tile's ds_reads done before overwrite
#pragma unroll
    for (int q = 0; q < 4; ++q) {
      const int row = w * 32 + q * 8 + srow;
      __builtin_amdgcn_global_load_lds(
          (const __attribute__((address_space(1))) void*)
              (gA + (size_t)row * E_DIM + k0 + skc),
          (__attribute__((address_space(3))) void*)(sA + (w * 32 + q * 8) * 32),
          16, 0, 0);
      __builtin_amdgcn_global_load_lds(
          (const __attribute__((address_space(1))) void*)
              (gB + (size_t)row * E_DIM + k0 + skc),
          (__attribute__((address_space(3))) void*)(sB + (w * 32 + q * 8) * 32),
          16, 0, 0);
    }
    __syncthreads();  // drains vmcnt (staging) before ds_read

    bf16x8 af[4], bfr[4];
    const int s7 = l15 & 7;   // row&7 for all fragment rows (offsets are %8==0)
    const int q2 = quad << 1; // first data chunk of this lane's 8 floats
#pragma unroll
    for (int i = 0; i < 4; ++i)
      af[i] = pack8_swz(sA + (wm * 64 + i * 16 + l15) * 32, q2, s7);
#pragma unroll
    for (int j = 0; j < 4; ++j)
      bfr[j] = pack8_swz(sB + (wn * 64 + j * 16 + l15) * 32, q2, s7);
#pragma unroll
    for (int i = 0; i < 4; ++i)
#pragma unroll
      for (int j = 0; j < 4; ++j)
        acc[i][j] = __builtin_amdgcn_mfma_f32_16x16x32_bf16(
            af[i], bfr[j], acc[i][j], 0, 0, 0);
  }

  // Epilogue. C/D layout: col = l15, row = quad*4 + r.
  // m = m0 + wm*64 + i*16 + quad*4 + r; m0%128==0 -> n = i*16 + quad*4 + r.
  // a = a0 + wn*64 + j*16 + l15.
  float vj[4];
#pragma unroll
  for (int j = 0; j < 4; ++j) vj[j] = vv[a0 + wn * 64 + j * 16 + l15];

#pragma unroll
  for (int i = 0; i < 4; ++i) {
#pragma unroll
    for (int r = 0; r < 4; ++r) {
      const int n = i * 16 + quad * 4 + r;
      const float* dp = dproj + n * A_DIM + a0 + wn * 64 + l15;
      float s = 0.f;
#pragma unroll
      for (int j = 0; j < 4; ++j) {
        float x = acc[i][j][r] + dp[j * 16];
        s += fast_tanh(x) * vj[j];
      }
      // reduce over the 16 column-lanes (masks < 16 stay within the 16-group)
      s += __shfl_xor(s, 1, 64);
      s += __shfl_xor(s, 2, 64);
      s += __shfl_xor(s, 4, 64);
      s += __shfl_xor(s, 8, 64);
      if (l15 == 0) atomicAdd(scores + m0 + wm * 64 + n, s);
    }
  }
}

// ---------------------------------------------------------------------------
// Kernel 3: softmax over T for each n; writes alpha fp32 into d_out[N*E ...].
// ---------------------------------------------------------------------------
__global__ __launch_bounds__(256) void softmax_kernel(
    const float* __restrict__ scores, float* __restrict__ out) {
  const int n   = blockIdx.x;
  const int tid = threadIdx.x;
  __shared__ float red[256];

  float vals[8];
  float mx = -1e30f;
#pragma unroll
  for (int i = 0; i < 8; ++i) {
    float sc = scores[(tid + i * 256) * N_DIM + n];
    vals[i] = sc;
    mx = fmaxf(mx, sc);
  }
  red[tid] = mx;
  __syncthreads();
  for (int s = 128; s > 0; s >>= 1) {
    if (tid < s) red[tid] = fmaxf(red[tid], red[tid + s]);
    __syncthreads();
  }
  mx = red[0];
  __syncthreads();

  float ssum = 0.f;
#pragma unroll
  for (int i = 0; i < 8; ++i) {
    vals[i] = __expf(vals[i] - mx);
    ssum += vals[i];
  }
  red[tid] = ssum;
  __syncthreads();
  for (int s = 128; s > 0; s >>= 1) {
    if (tid < s) red[tid] += red[tid + s];
    __syncthreads();
  }
  const float inv = 1.0f / red[0];

#pragma unroll
  for (int i = 0; i < 8; ++i) {
    const int t = tid + i * 256;
    out[N_DIM * E_DIM + t * N_DIM + n] = vals[i] * inv;  // alpha after ctx
  }
}

// ---------------------------------------------------------------------------
// Kernel 4: ctx_f32[n][e] += sum_t alpha[t][n] * enc[t][n][e]
// grid (16 t-chunks, 64 n), 256 threads, 4 e's per thread (float4 loads).
// alpha is read back from d_out (written by softmax_kernel, same stream).
// ---------------------------------------------------------------------------
__global__ __launch_bounds__(256) void ctx_kernel(
    const float* __restrict__ enc, const float* __restrict__ alpha,
    float* __restrict__ ctxf) {
  const int tc  = blockIdx.x;  // 0..15
  const int n   = blockIdx.y;  // 0..63
  const int tid = threadIdx.x;
  const int e   = tid * 4;
  float a0 = 0.f, a1 = 0.f, a2 = 0.f, a3 = 0.f;
  const int tbeg = tc * 128;
#pragma unroll 4
  for (int t = tbeg; t < tbeg + 128; ++t) {
    float al = alpha[t * N_DIM + n];
    const float* p = enc + ((size_t)(t * N_DIM + n)) * E_DIM + e;
    floatx4 u = *(const floatx4*)p;
    a0 += al * u[0];
    a1 += al * u[1];
    a2 += al * u[2];
    a3 += al * u[3];
  }
  float* c = ctxf + n * E_DIM + e;
  atomicAdd(c + 0, a0);
  atomicAdd(c + 1, a1);
  atomicAdd(c + 2, a2);
  atomicAdd(c + 3, a3);
}

// ---------------------------------------------------------------------------
// Kernel 5: copy ctx fp32 -> d_out[0 .. N*E)
// ---------------------------------------------------------------------------
__global__ __launch_bounds__(256) void copy_ctx(
    const float* __restrict__ ctxf, float* __restrict__ out) {
  const int i = blockIdx.x * 256 + threadIdx.x;
  out[i] = ctxf[i];
}

// ---------------------------------------------------------------------------
// Workspace layout (floats):
//   [0, 131072)          scores   (zeroed)
//   [131072, 196608)     ctx_f32  (zeroed)
//   [196608, 229376)     d_proj
// total 896 KB
// ---------------------------------------------------------------------------
extern "C" void kernel_launch(void* const* d_in, const int* in_sizes, int n_in,
                              void* d_out, int out_size, void* d_ws,
                              size_t ws_size, hipStream_t stream) {
  const float* enc   = (const float*)d_in[0];
  const float* dec_h = (const float*)d_in[1];
  const float* W_e   = (const float*)d_in[2];
  const float* W_d   = (const float*)d_in[3];
  const float* v     = (const float*)d_in[4];
  float* out = (float*)d_out;
  float* ws  = (float*)d_ws;

  float* scores = ws;
  float* ctxf   = ws + 131072;
  float* dproj  = ws + 196608;

  // scores + ctxf are accumulated with atomics -> zero them (ws is poisoned)
  hipMemsetAsync(scores, 0, (size_t)(131072 + 65536) * sizeof(float), stream);

  dproj_kernel<<<512, 256, 0, stream>>>(dec_h, W_d, dproj);
  score_gemm<<<dim3(4, 1024), 256, 0, stream>>>(enc, W_e, dproj, v, scores);
  softmax_kernel<<<64, 256, 0, stream>>>(scores, out);
  ctx_kernel<<<dim3(16, 64), 256, 0, stream>>>(enc, out + N_DIM * E_DIM, ctxf);
  copy_ctx<<<256, 256, 0, stream>>>(ctxf, out);
}